// Round 12
// baseline (1548.026 us; speedup 1.0000x reference)
//
#include <hip/hip_runtime.h>
#include <hip/hip_fp16.h>

// Workspace: 384 MiB.
//   A [0,128M):   q_h (64M) -> k_h/k_l -> qk (f32, 128M)
//   D [128,256M): qT_h/qT_l -> P (64M) + vT (64M)
//   E [256,384M): kk_h (64M) + val_h (64M)
// d_out scratch (dead before final GEMM): wq_h/l, wk_h, wv_h

using half8_t = __attribute__((ext_vector_type(8))) _Float16;
using f32x4   = __attribute__((ext_vector_type(4))) float;

static constexpr int NB = 8;
static constexpr int Sd = 2048;
static constexpr long MAT = (long)Sd * Sd;

__device__ __forceinline__ void gload16(const _Float16* g, _Float16* l) {
  __builtin_amdgcn_global_load_lds(
      (const __attribute__((address_space(1))) void*)g,
      (__attribute__((address_space(3))) void*)l, 16, 0, 0);
}
__device__ __forceinline__ void barrier_() { asm volatile("s_barrier" ::: "memory"); }
__device__ __forceinline__ void lgkm0_()   { asm volatile("s_waitcnt lgkmcnt(0)" ::: "memory"); }
#define VMCNT(n) asm volatile("s_waitcnt vmcnt(" #n ")" ::: "memory")
#define SCHEDB() __builtin_amdgcn_sched_barrier(0)
#define INC5(x) x = ((x) == 4 ? 0 : (x) + 1)

// ---------------------------------------------------------------------------
// presplit: f32 -> fp16 hi (+ residual lo if SPLIT), scaled.
// ---------------------------------------------------------------------------
template<bool SPLIT>
__global__ __launch_bounds__(256) void presplit(const float* __restrict__ in,
    _Float16* __restrict__ h, _Float16* __restrict__ l, long n8, float scl)
{
  long i = (long)blockIdx.x * 256 + threadIdx.x;
  const long stride = (long)gridDim.x * 256;
  for (; i < n8; i += stride) {
    const f32x4* p = (const f32x4*)(in + i * 8);
    f32x4 a = p[0], b = p[1];
    half8_t hh, ll;
#pragma unroll
    for (int j = 0; j < 4; j++) {
      float x = a[j] * scl; _Float16 hv = (_Float16)x;
      hh[j] = hv; if constexpr (SPLIT) ll[j] = (_Float16)(x - (float)hv);
      float y = b[j] * scl; _Float16 hw = (_Float16)y;
      hh[4 + j] = hw; if constexpr (SPLIT) ll[4 + j] = (_Float16)(y - (float)hw);
    }
    *(half8_t*)(h + i * 8) = hh;
    if constexpr (SPLIT) *(half8_t*)(l + i * 8) = ll;
  }
}

// ---------------------------------------------------------------------------
// gemm12 (B^T form): C[i][j] = cscale * sum_k A[i][k]*B[j][k] (+ bias)
// ANTI-PHASE WAVE-GROUP variant of gemm10. 256x256 tile, 8 waves; unit =
// K-32 slab (256x32, 16KB/operand), ring-of-FIVE -> 160KiB LDS, 1 block/CU.
// G0 (w<4, N cols 0..127):  register read-AHEAD — per iter j:
//   {mfma32(unit j, frags pre-read) ; readF(unit j+1 -> alt set)}
// G1 (w>=4, N cols 128..255): read-BEHIND — per iter j:
//   {readF(unit j-1) ; lgkm0 ; mfma32(unit j-1)}
// Both: stage(unit j+3) ; vmcnt(4) [forces stage j+2] ; barrier.
// Per SIMD (round-robin wave placement): one MFMA-first + one read-first
// wave per window -> matrix pipe and LDS pipe busy simultaneously.
// Hazards (ring-5): stage(j+3)->slot (j-2)%5; readers G0@j-3, G1@j-1 both
// complete pre-barrier(j-1); stage issues post-barrier(j-1).  Publication:
// stage(j+1) forced by vmcnt(4)@j-1, barrier(j-1); G0 reads it at j.
// NSEG: 1 plain (K=2048); 2 = K-concat split [Ah|Al]x[Bh|Bh] (K=4096).
// BIAS: 0 none, 1 bias[n], 2 bias[m].
// OUT: 0 f32, 1 fp16, 2 split fp16 (x16), 3 fp16 hi-only (x16).
// ---------------------------------------------------------------------------
template<int NSEG, int BIAS, int OUT>
__global__ __launch_bounds__(512, 2) void gemm12(
    const _Float16* __restrict__ Ah, const _Float16* __restrict__ Al, long sA,
    const _Float16* __restrict__ Bh, long sB,
    const float* __restrict__ bias, float cscale,
    void* __restrict__ Cp, void* __restrict__ Clp, long sC)
{
  constexpr int H = NSEG * 64;      // K-32 units
  __shared__ __align__(16) _Float16 LA[5][8192];   // ring of 5 x 16KB
  __shared__ __align__(16) _Float16 LB[5][8192];

  const int t = threadIdx.x, w = t >> 6, l = t & 63;
  const int grp = w >> 2;           // 0: read-ahead, 1: read-behind

  // XCD swizzle: 512 wgs -> 64 consecutive per XCD (one batch per XCD)
  const int wg = blockIdx.x;
  const int swz = (wg & 7) * 64 + (wg >> 3);
  const int bz = swz >> 6, rem = swz & 63;
  const int by = rem >> 3, bx = rem & 7;

  const _Float16* PAh = Ah + (size_t)bz * sA + (size_t)(by * 256) * Sd;
  const _Float16* PBh = Bh + (size_t)bz * sB + (size_t)(bx * 256) * Sd;
  const _Float16* PAl = (NSEG == 2)
      ? Al + (size_t)bz * sA + (size_t)(by * 256) * Sd : PAh;

  // staging geometry (r10 verbatim): slot S = i*512 + t -> row 2*(S>>3)+(S&1),
  // k-slot lk = ((S&7)>>1) ^ ((S>>3)&3); dest LDS = linear slot*8.
  const int s7 = t & 7;
  const int lkS = (s7 >> 1) ^ ((t >> 3) & 3);
  const size_t srcoff = (size_t)(2 * (t >> 3) + (s7 & 1)) * Sd + lkS * 8;
  const int du0 = w * 512;

  // read geometry (r10 involution, measured conflict-free); G1 shifts N +128
  const int wq2 = w & 3;
  const int wm = (wq2 >> 1) * 128, wn = (wq2 & 1) * 64 + grp * 128;
  const int lm = l & 15, lkr = l >> 4;
  const int sprime = ((lkr ^ ((lm >> 1) & 3)) << 1) | (lm & 1);
  const int aoff = (wm >> 1) * 128 + (lm >> 1) * 128 + sprime * 16;
  const int boff = (wn >> 1) * 128 + (lm >> 1) * 128 + sprime * 16;

  auto srcA = [&](int hp) -> const _Float16* {
    if constexpr (NSEG == 2) return (hp >> 6) ? PAl : PAh;
    return PAh;
  };
  auto koOf = [&](int hp) -> int {
    if constexpr (NSEG == 2) return (hp & 63) * 32;
    return hp * 32;
  };
  auto stageP = [&](int hp, int slot) {   // 4 global_load_lds
    const _Float16* a = srcA(hp) + koOf(hp);
    const _Float16* b = PBh + koOf(hp);
    gload16(a + srcoff, LA[slot] + du0);
    gload16(a + srcoff + (size_t)128 * Sd, LA[slot] + du0 + 4096);
    gload16(b + srcoff, LB[slot] + du0);
    gload16(b + srcoff + (size_t)128 * Sd, LB[slot] + du0 + 4096);
  };

  f32x4 acc[8][4] = {};
  half8_t fa0[8], fb0[4], fa1[8], fb1[4];   // G0 dbuf; G1 uses set 0 only

  auto readF = [&](int slot, half8_t (&fa)[8], half8_t (&fb)[4]) {  // 12 b128
#pragma unroll
    for (int f = 0; f < 8; f++)
      fa[f] = *(const half8_t*)((const char*)LA[slot] + aoff + f * 1024);
#pragma unroll
    for (int n = 0; n < 4; n++)
      fb[n] = *(const half8_t*)((const char*)LB[slot] + boff + n * 1024);
  };
  auto mfma32 = [&](const half8_t (&fa)[8], const half8_t (&fb)[4]) {
    __builtin_amdgcn_s_setprio(1);
#pragma unroll
    for (int f = 0; f < 8; f++)
#pragma unroll
      for (int n = 0; n < 4; n++)
        acc[f][n] = __builtin_amdgcn_mfma_f32_16x16x32_f16(fa[f], fb[n], acc[f][n], 0, 0, 0);
    __builtin_amdgcn_s_setprio(0);
  };

  // ---- prologue: stage units 0,1,2; force 0,1; publish; G0 pre-reads unit 0
  stageP(0, 0); stageP(1, 1); stageP(2, 2);
  VMCNT(4);
  barrier_();
  if (grp == 0) readF(0, fa0, fb0);

  // ---- main loop: iters j = 0..H (inclusive), unrolled x2 (H even)
  int sm1 = 4, sp1 = 1, sp3 = 3;   // slots of j-1, j+1, j+3 (mod 5)

#define ITER(J, CONS_A, CONS_B, NEXT_A, NEXT_B)                               \
  {                                                                           \
    const int j_ = (J);                                                       \
    if (grp == 0) {                                                           \
      if (j_ < H) { SCHEDB(); mfma32(CONS_A, CONS_B); SCHEDB(); }             \
      if (j_ + 1 < H) readF(sp1, NEXT_A, NEXT_B);                             \
    } else {                                                                  \
      if (j_ >= 1) {                                                          \
        readF(sm1, fa0, fb0); lgkm0_(); SCHEDB(); mfma32(fa0, fb0); SCHEDB(); \
      }                                                                       \
    }                                                                         \
    if (j_ + 3 < H)       { stageP(j_ + 3, sp3); VMCNT(4); }                  \
    else if (j_ + 3 == H) { VMCNT(0); }                                       \
    if (j_ < H) barrier_();                                                   \
    INC5(sm1); INC5(sp1); INC5(sp3);                                          \
  }

  for (int j = 0; j <= H; j += 2) {
    ITER(j, fa0, fb0, fa1, fb1)
    if (j + 1 <= H) ITER(j + 1, fa1, fb1, fa0, fb0)
  }
#undef ITER

  // ---- epilogue: C/D layout col = lane&15, row = (lane>>4)*4 + reg
  const int row_base = by * 256 + wm + (lkr << 2);
  const int col_base = bx * 256 + wn + lm;
#pragma unroll
  for (int fm = 0; fm < 8; fm++)
#pragma unroll
    for (int fn = 0; fn < 4; fn++) {
      const int n = col_base + fn * 16;
      float bcol = 0.f;
      if constexpr (BIAS == 1) bcol = bias[n];
#pragma unroll
      for (int r = 0; r < 4; r++) {
        const int m = row_base + fm * 16 + r;
        float v = acc[fm][fn][r] * cscale;
        if constexpr (BIAS == 1) v += bcol;
        if constexpr (BIAS == 2) v += bias[m];
        const size_t ci = (size_t)bz * sC + (size_t)m * Sd + n;
        if constexpr (OUT == 0) ((float*)Cp)[ci] = v;
        else if constexpr (OUT == 1) ((_Float16*)Cp)[ci] = (_Float16)v;
        else if constexpr (OUT == 3) ((_Float16*)Cp)[ci] = (_Float16)(v * 16.0f);
        else {
          float sv = v * 16.0f;
          _Float16 hv = (_Float16)sv;
          ((_Float16*)Cp)[ci]  = hv;
          ((_Float16*)Clp)[ci] = (_Float16)(sv - (float)hv);
        }
      }
    }
}

// ---------------------------------------------------------------------------
// Row softmax: one 256-thread block per row of 2048 f32 -> fp16 probs.
// ---------------------------------------------------------------------------
__global__ __launch_bounds__(256) void softmax_rows(const float* __restrict__ X,
                                                    _Float16* __restrict__ P)
{
  __shared__ float red[4];
  const size_t row = blockIdx.x;
  const float* x = X + row * Sd;
  _Float16* p = P + row * Sd;
  const int t = threadIdx.x;
  float v[8];
  float mx = -1e30f;
#pragma unroll
  for (int i = 0; i < 8; i++) { v[i] = x[t + 256 * i]; mx = fmaxf(mx, v[i]); }
#pragma unroll
  for (int o = 32; o > 0; o >>= 1) mx = fmaxf(mx, __shfl_xor(mx, o, 64));
  if ((t & 63) == 0) red[t >> 6] = mx;
  __syncthreads();
  mx = fmaxf(fmaxf(red[0], red[1]), fmaxf(red[2], red[3]));
  __syncthreads();
  float s = 0.f;
#pragma unroll
  for (int i = 0; i < 8; i++) { v[i] = __expf(v[i] - mx); s += v[i]; }
#pragma unroll
  for (int o = 32; o > 0; o >>= 1) s += __shfl_xor(s, o, 64);
  if ((t & 63) == 0) red[t >> 6] = s;
  __syncthreads();
  s = red[0] + red[1] + red[2] + red[3];
  float inv = 1.f / s;
#pragma unroll
  for (int i = 0; i < 8; i++) p[t + 256 * i] = (_Float16)(v[i] * inv);
}

// ---------------------------------------------------------------------------
extern "C" void kernel_launch(void* const* d_in, const int* in_sizes, int n_in,
                              void* d_out, int out_size, void* d_ws, size_t ws_size,
                              hipStream_t stream)
{
  const float* query = (const float*)d_in[0];
  const float* key_  = (const float*)d_in[1];
  const float* value = (const float*)d_in[2];
  const float* Wq = (const float*)d_in[3];
  const float* bq = (const float*)d_in[4];
  const float* Wk = (const float*)d_in[5];
  const float* bk = (const float*)d_in[6];
  const float* Wv = (const float*)d_in[7];
  const float* bv = (const float*)d_in[8];

  char* ws = (char*)d_ws;
  char* ob = (char*)d_out;
  const size_t M64 = (size_t)NB * MAT * 2;   // 64 MiB

  _Float16* q_h  = (_Float16*)(ws);                 // A[0,64)
  _Float16* k_h  = (_Float16*)(ws);                 // A[0,64) (q dead)
  _Float16* k_l  = (_Float16*)(ws + M64);           // A[64,128)
  float*    qk   = (float*)(ws);                    // A as f32 (k dead)
  _Float16* qT_h = (_Float16*)(ws + 2 * M64);       // D[128,192)
  _Float16* qT_l = (_Float16*)(ws + 3 * M64);       // D[192,256)
  _Float16* P    = qT_h;                            // after qT dead
  _Float16* vT   = qT_l;
  _Float16* kk_h = (_Float16*)(ws + 4 * M64);       // E[256,320)
  _Float16* val_h = (_Float16*)(ws + 5 * M64);      // E[320,384)

  _Float16* wq_h = (_Float16*)(ob);
  _Float16* wq_l = (_Float16*)(ob + (MAT * 2));
  _Float16* wk_h = (_Float16*)(ob + 2 * (MAT * 2));
  _Float16* wv_h = (_Float16*)(ob + 3 * (MAT * 2));
  float* out = (float*)d_out;

  dim3 blk256(256), blk512(512);
  dim3 gg(512);   // 8 batches x 8x8 tiles of 256
  const long NQ8 = (long)NB * MAT / 8;
  const long NW8 = MAT / 8;

  // 1. presplit query (hi only, x16), Wq (hi+lo, x16)
  presplit<false><<<dim3(2048), blk256, 0, stream>>>(query, q_h, nullptr, NQ8, 16.f);
  presplit<true><<<dim3(2048), blk256, 0, stream>>>(Wq, wq_h, wq_l, NW8, 16.f);
  // 2. qT[e][s] = sum_d Wq[e][d]*query[s][d] + bq[e] (row bias), split out
  gemm12<2, 2, 2><<<gg, blk512, 0, stream>>>(wq_h, wq_l, 0, q_h, MAT,
                                             bq, 1.f / 256.f, qT_h, qT_l, MAT);
  // 3. presplit key_ (hi+lo, x16), Wk (hi only, x16)
  presplit<true><<<dim3(2048), blk256, 0, stream>>>(key_, k_h, k_l, NQ8, 16.f);
  presplit<false><<<dim3(2048), blk256, 0, stream>>>(Wk, wk_h, nullptr, NW8, 16.f);
  // 4. kk[s'][e] = sum_d key_[s'][d]*Wk[e][d] + bk[e] (col bias), hi-only out
  gemm12<2, 1, 3><<<gg, blk512, 0, stream>>>(k_h, k_l, MAT, wk_h, 0,
                                             bk, 1.f / 256.f, kk_h, nullptr, MAT);
  // 5. qk[e][s'] = sum_m qT[e][m]*kk[s'][m]  (f32 out)
  gemm12<2, 0, 0><<<gg, blk512, 0, stream>>>(qT_h, qT_l, MAT, kk_h, MAT,
                                             nullptr, 1.f / 256.f, qk, nullptr, MAT);
  // 6. P = row-softmax(qk), fp16
  softmax_rows<<<dim3(NB * Sd), blk256, 0, stream>>>(qk, P);
  // 7. presplit value (x1), Wv (x1)
  presplit<false><<<dim3(2048), blk256, 0, stream>>>(value, val_h, nullptr, NQ8, 1.f);
  presplit<false><<<dim3(2048), blk256, 0, stream>>>(Wv, wv_h, nullptr, NW8, 1.f);
  // 8. vT[d'][s'] = sum_d Wv[d'][d]*value[s'][d] + bv[d'] (row bias), fp16
  gemm12<1, 2, 1><<<gg, blk512, 0, stream>>>(wv_h, nullptr, 0, val_h, MAT,
                                             bv, 1.f, vT, nullptr, MAT);
  // 9. out[d'][e] = sum_s' vT[d'][s']*P[e][s']  (f32 -> d_out)
  gemm12<1, 0, 0><<<gg, blk512, 0, stream>>>(vT, nullptr, MAT, P, MAT,
                                             nullptr, 1.f, out, nullptr, MAT);
}

// Round 13
// 1306.034 us; speedup vs baseline: 1.1853x; 1.1853x over previous
//
#include <hip/hip_runtime.h>
#include <hip/hip_fp16.h>

// Workspace: 384 MiB.
//   A [0,128M):   q_h (64M) -> k_h/k_l -> qk (f32, 128M)
//   D [128,256M): qT_h/qT_l -> P (64M) + vT (64M)
//   E [256,384M): kk_h (64M) + val_h (64M)
// d_out scratch (dead before final GEMM): wq_h/l, wk_h, wv_h

using half8_t = __attribute__((ext_vector_type(8))) _Float16;
using f32x4   = __attribute__((ext_vector_type(4))) float;
using f32x16  = __attribute__((ext_vector_type(16))) float;

static constexpr int NB = 8;
static constexpr int Sd = 2048;
static constexpr long MAT = (long)Sd * Sd;

__device__ __forceinline__ void gload16(const _Float16* g, _Float16* l) {
  __builtin_amdgcn_global_load_lds(
      (const __attribute__((address_space(1))) void*)g,
      (__attribute__((address_space(3))) void*)l, 16, 0, 0);
}
// gemm10's measured-best sync artifact: memory-clobbered barrier/vmcnt.
__device__ __forceinline__ void barrier_() { asm volatile("s_barrier" ::: "memory"); }
#define VMCNT(n) asm volatile("s_waitcnt vmcnt(" #n ")" ::: "memory")
#define SCHEDB() __builtin_amdgcn_sched_barrier(0)

// ---------------------------------------------------------------------------
// presplit: f32 -> fp16 hi (+ residual lo if SPLIT), scaled.
// ---------------------------------------------------------------------------
template<bool SPLIT>
__global__ __launch_bounds__(256) void presplit(const float* __restrict__ in,
    _Float16* __restrict__ h, _Float16* __restrict__ l, long n8, float scl)
{
  long i = (long)blockIdx.x * 256 + threadIdx.x;
  const long stride = (long)gridDim.x * 256;
  for (; i < n8; i += stride) {
    const f32x4* p = (const f32x4*)(in + i * 8);
    f32x4 a = p[0], b = p[1];
    half8_t hh, ll;
#pragma unroll
    for (int j = 0; j < 4; j++) {
      float x = a[j] * scl; _Float16 hv = (_Float16)x;
      hh[j] = hv; if constexpr (SPLIT) ll[j] = (_Float16)(x - (float)hv);
      float y = b[j] * scl; _Float16 hw = (_Float16)y;
      hh[4 + j] = hw; if constexpr (SPLIT) ll[4 + j] = (_Float16)(y - (float)hw);
    }
    *(half8_t*)(h + i * 8) = hh;
    if constexpr (SPLIT) *(half8_t*)(l + i * 8) = ll;
  }
}

// ---------------------------------------------------------------------------
// gemm13 (B^T form): C[i][j] = cscale * sum_k A[i][k]*B[j][k] (+ bias)
// gemm10 schedule + 32x32x16 MFMA (r9-verified layout) + shared-B for splits.
// 256x256 tile, 8 waves (4 row x 2 col, wave tile 64x128), 512 threads.
// Unit = K-32 slab (256x32, 16KB). A ring-4 (64KB) + B ring-4 (64KB) = 128KB.
// LDS unit layout (r9-verified, 0 conflicts): elem(r,o) = (r>>4)*512 +
//   o*128 + (r&15)*8  (o = k-octet 0..3). Stage: gload i -> row i*128 +
//   w*16 + (l&15), octet l>>4; dest linear w*512 (+4096 for i=1).
// NSEG==2 (split [Ah|Al] x shared Bh, K=2048 x 2 segs): per unit k, two
//   phases {hi, lo}; B(k) staged once, frags read once (even phase), reused
//   from regs in odd phase. Per phase: read-ahead A-dbuf, 1 vmcnt + 1 bar.
// NSEG==1 (plain): unit = phase; A read-ahead dbuf, B same-phase single set.
// BIAS: 0 none, 1 bias[n], 2 bias[m].
// OUT: 0 f32, 1 fp16, 2 split fp16 (x16), 3 fp16 hi-only (x16).
// ---------------------------------------------------------------------------
template<int NSEG, int BIAS, int OUT>
__global__ __launch_bounds__(512, 2) void gemm13(
    const _Float16* __restrict__ Ah, const _Float16* __restrict__ Al, long sA,
    const _Float16* __restrict__ Bh, long sB,
    const float* __restrict__ bias, float cscale,
    void* __restrict__ Cp, void* __restrict__ Clp, long sC)
{
  constexpr int H = 64;             // K-32 units (K = 2048)
  __shared__ __align__(16) _Float16 LA[4][8192];   // ring-4 x 16KB
  __shared__ __align__(16) _Float16 LB[4][8192];

  const int t = threadIdx.x, w = t >> 6, l = t & 63;

  // XCD swizzle: 512 wgs -> 64 consecutive per XCD (one batch per XCD)
  const int wg = blockIdx.x;
  const int swz = (wg & 7) * 64 + (wg >> 3);
  const int bz = swz >> 6, rem = swz & 63;
  const int by = rem >> 3, bx = rem & 7;

  const _Float16* PAh = Ah + (size_t)bz * sA + (size_t)(by * 256) * Sd;
  const _Float16* PBh = Bh + (size_t)bz * sB + (size_t)(bx * 256) * Sd;
  const _Float16* PAl = (NSEG == 2)
      ? Al + (size_t)bz * sA + (size_t)(by * 256) * Sd : PAh;

  // staging source (r9 decode, 512-thread scale): gload i covers
  // row i*128 + w*16 + (l&15), k-octet l>>4.
  const size_t srcoff = (size_t)(w * 16 + (l & 15)) * Sd + (size_t)((l >> 4) * 8);
  const int du0 = w * 512;   // dest elems (+ HW lane*8); i=1 adds 4096

  // read geometry (r9 formula): frag (rt/ct, ks) at
  //   woff*64 + rt*2048 + ks*512 + laneoff
  const int wm = (w >> 1) * 64, wn = (w & 1) * 128;
  const int laneoff = ((l >> 4) & 1) * 1024 + (l >> 5) * 256 + (l & 15) * 16;
  const int aoff = wm * 64 + laneoff;
  const int boff = wn * 64 + laneoff;

  auto stageA = [&](int p) {   // A-phase p (split: unit p>>1, seg p&1)
    const int slot = p & 3;
    const _Float16* base;
    if constexpr (NSEG == 2)
      base = ((p & 1) ? PAl : PAh) + (p >> 1) * 32;
    else
      base = PAh + p * 32;
    gload16(base + srcoff, LA[slot] + du0);
    gload16(base + srcoff + (size_t)128 * Sd, LA[slot] + du0 + 4096);
  };
  auto stageB = [&](int k) {
    const int slot = k & 3;
    const _Float16* base = PBh + k * 32;
    gload16(base + srcoff, LB[slot] + du0);
    gload16(base + srcoff + (size_t)128 * Sd, LB[slot] + du0 + 4096);
  };

  f32x16 acc[2][4] = {};
  half8_t a0[4], a1[4], b[8];

  auto readA = [&](int slot, half8_t (&fa)[4]) {   // 4 ds_read_b128
#pragma unroll
    for (int rt = 0; rt < 2; rt++)
#pragma unroll
      for (int ks = 0; ks < 2; ks++)
        fa[rt * 2 + ks] =
            *(const half8_t*)((const char*)LA[slot] + aoff + rt * 2048 + ks * 512);
  };
  auto readB = [&](int slot) {                     // 8 ds_read_b128
#pragma unroll
    for (int ct = 0; ct < 4; ct++)
#pragma unroll
      for (int ks = 0; ks < 2; ks++)
        b[ct * 2 + ks] =
            *(const half8_t*)((const char*)LB[slot] + boff + ct * 2048 + ks * 512);
  };
  auto mfma16 = [&](const half8_t (&fa)[4]) {      // 16 x 32x32x16
    __builtin_amdgcn_s_setprio(1);
#pragma unroll
    for (int ks = 0; ks < 2; ks++)
#pragma unroll
      for (int rt = 0; rt < 2; rt++)
#pragma unroll
        for (int ct = 0; ct < 4; ct++)
          acc[rt][ct] = __builtin_amdgcn_mfma_f32_32x32x16_f16(
              fa[rt * 2 + ks], b[ct * 2 + ks], acc[rt][ct], 0, 0, 0);
    __builtin_amdgcn_s_setprio(0);
  };

  if constexpr (NSEG == 2) {
    // prologue: A0,B0,A1,A2,B1 (10 loads); force A0,B0,A1; publish
    stageA(0); stageB(0); stageA(1); stageA(2); stageB(1);
    VMCNT(4);
    barrier_();
    readA(0, a0);

    for (int k = 0; k < H; ++k) {
      // even phase 2k: consume Ah(k)*B(k); read A(2k+1), B(k)
      readA((2 * k + 1) & 3, a1);
      readB(k & 3);
      if (k + 2 < H)      { stageA(2 * k + 3); stageB(k + 2); }
      else if (k + 1 < H) { stageA(2 * k + 3); }
      SCHEDB();
      mfma16(a0);
      if (k + 2 < H)      { VMCNT(4); }
      else if (k + 1 < H) { VMCNT(2); }
      else                { VMCNT(0); }
      barrier_();
      // odd phase 2k+1: consume Al(k)*B(k) (b reused); read A(2k+2)
      if (k + 1 < H) readA((2 * k + 2) & 3, a0);
      if (k + 2 < H) stageA(2 * k + 4);
      SCHEDB();
      mfma16(a1);
      if (k + 2 < H)      { VMCNT(2); }
      else if (k + 1 < H) { VMCNT(0); }
      if (k + 1 < H) barrier_();
    }
  } else {
    // prologue: A0,B0,A1,B1,A2,B2 (12 loads); force A0,B0,A1; publish
    stageA(0); stageB(0); stageA(1); stageB(1); stageA(2); stageB(2);
    VMCNT(6);
    barrier_();
    readA(0, a0);

    for (int j = 0; j < H / 2; ++j) {
      {   // even unit u = 2j: consume a0
        const int u = 2 * j;
        readA((u + 1) & 3, a1);
        readB(u & 3);
        if (u + 3 < H) { stageA(u + 3); stageB(u + 3); }
        SCHEDB();
        mfma16(a0);
        if (u + 3 < H)       { VMCNT(4); }
        else if (u + 3 == H) { VMCNT(0); }
        barrier_();
      }
      {   // odd unit u = 2j+1: consume a1
        const int u = 2 * j + 1;
        if (u + 1 < H) readA((u + 1) & 3, a0);
        readB(u & 3);
        if (u + 3 < H) { stageA(u + 3); stageB(u + 3); }
        SCHEDB();
        mfma16(a1);
        if (u + 3 < H)       { VMCNT(4); }
        else if (u + 3 == H) { VMCNT(0); }
        if (u + 1 < H) barrier_();
      }
    }
  }

  // ---- epilogue (r9-verified 32x32 C/D layout): col = lane&31,
  //      row = (reg&3) + 8*(reg>>2) + 4*(lane>>5)
  const int hi = l >> 5;
  const int colb = bx * 256 + wn + (l & 31);
  const int rowb = by * 256 + wm + 4 * hi;
#pragma unroll
  for (int rt = 0; rt < 2; rt++)
#pragma unroll
    for (int ct = 0; ct < 4; ct++) {
      const int n = colb + ct * 32;
      float bcol = 0.f;
      if constexpr (BIAS == 1) bcol = bias[n];
#pragma unroll
      for (int r = 0; r < 16; r++) {
        const int m = rowb + rt * 32 + (r & 3) + 8 * (r >> 2);
        float v = acc[rt][ct][r] * cscale;
        if constexpr (BIAS == 1) v += bcol;
        if constexpr (BIAS == 2) v += bias[m];
        const size_t ci = (size_t)bz * sC + (size_t)m * Sd + n;
        if constexpr (OUT == 0) ((float*)Cp)[ci] = v;
        else if constexpr (OUT == 1) ((_Float16*)Cp)[ci] = (_Float16)v;
        else if constexpr (OUT == 3) ((_Float16*)Cp)[ci] = (_Float16)(v * 16.0f);
        else {
          float sv = v * 16.0f;
          _Float16 hv = (_Float16)sv;
          ((_Float16*)Cp)[ci]  = hv;
          ((_Float16*)Clp)[ci] = (_Float16)(sv - (float)hv);
        }
      }
    }
}

// ---------------------------------------------------------------------------
// Row softmax: one 256-thread block per row of 2048 f32 -> fp16 probs.
// ---------------------------------------------------------------------------
__global__ __launch_bounds__(256) void softmax_rows(const float* __restrict__ X,
                                                    _Float16* __restrict__ P)
{
  __shared__ float red[4];
  const size_t row = blockIdx.x;
  const float* x = X + row * Sd;
  _Float16* p = P + row * Sd;
  const int t = threadIdx.x;
  float v[8];
  float mx = -1e30f;
#pragma unroll
  for (int i = 0; i < 8; i++) { v[i] = x[t + 256 * i]; mx = fmaxf(mx, v[i]); }
#pragma unroll
  for (int o = 32; o > 0; o >>= 1) mx = fmaxf(mx, __shfl_xor(mx, o, 64));
  if ((t & 63) == 0) red[t >> 6] = mx;
  __syncthreads();
  mx = fmaxf(fmaxf(red[0], red[1]), fmaxf(red[2], red[3]));
  __syncthreads();
  float s = 0.f;
#pragma unroll
  for (int i = 0; i < 8; i++) { v[i] = __expf(v[i] - mx); s += v[i]; }
#pragma unroll
  for (int o = 32; o > 0; o >>= 1) s += __shfl_xor(s, o, 64);
  if ((t & 63) == 0) red[t >> 6] = s;
  __syncthreads();
  s = red[0] + red[1] + red[2] + red[3];
  float inv = 1.f / s;
#pragma unroll
  for (int i = 0; i < 8; i++) p[t + 256 * i] = (_Float16)(v[i] * inv);
}

// ---------------------------------------------------------------------------
extern "C" void kernel_launch(void* const* d_in, const int* in_sizes, int n_in,
                              void* d_out, int out_size, void* d_ws, size_t ws_size,
                              hipStream_t stream)
{
  const float* query = (const float*)d_in[0];
  const float* key_  = (const float*)d_in[1];
  const float* value = (const float*)d_in[2];
  const float* Wq = (const float*)d_in[3];
  const float* bq = (const float*)d_in[4];
  const float* Wk = (const float*)d_in[5];
  const float* bk = (const float*)d_in[6];
  const float* Wv = (const float*)d_in[7];
  const float* bv = (const float*)d_in[8];

  char* ws = (char*)d_ws;
  char* ob = (char*)d_out;
  const size_t M64 = (size_t)NB * MAT * 2;   // 64 MiB

  _Float16* q_h  = (_Float16*)(ws);                 // A[0,64)
  _Float16* k_h  = (_Float16*)(ws);                 // A[0,64) (q dead)
  _Float16* k_l  = (_Float16*)(ws + M64);           // A[64,128)
  float*    qk   = (float*)(ws);                    // A as f32 (k dead)
  _Float16* qT_h = (_Float16*)(ws + 2 * M64);       // D[128,192)
  _Float16* qT_l = (_Float16*)(ws + 3 * M64);       // D[192,256)
  _Float16* P    = qT_h;                            // after qT dead
  _Float16* vT   = qT_l;
  _Float16* kk_h = (_Float16*)(ws + 4 * M64);       // E[256,320)
  _Float16* val_h = (_Float16*)(ws + 5 * M64);      // E[320,384)

  _Float16* wq_h = (_Float16*)(ob);
  _Float16* wq_l = (_Float16*)(ob + (MAT * 2));
  _Float16* wk_h = (_Float16*)(ob + 2 * (MAT * 2));
  _Float16* wv_h = (_Float16*)(ob + 3 * (MAT * 2));
  float* out = (float*)d_out;

  dim3 blk256(256), blk512(512);
  dim3 gg(512);   // 8 batches x 8x8 tiles of 256
  const long NQ8 = (long)NB * MAT / 8;
  const long NW8 = MAT / 8;

  // 1. presplit query (hi only, x16), Wq (hi+lo, x16)
  presplit<false><<<dim3(2048), blk256, 0, stream>>>(query, q_h, nullptr, NQ8, 16.f);
  presplit<true><<<dim3(2048), blk256, 0, stream>>>(Wq, wq_h, wq_l, NW8, 16.f);
  // 2. qT[e][s] = sum_d Wq[e][d]*query[s][d] + bq[e] (row bias), split out
  gemm13<2, 2, 2><<<gg, blk512, 0, stream>>>(wq_h, wq_l, 0, q_h, MAT,
                                             bq, 1.f / 256.f, qT_h, qT_l, MAT);
  // 3. presplit key_ (hi+lo, x16), Wk (hi only, x16)
  presplit<true><<<dim3(2048), blk256, 0, stream>>>(key_, k_h, k_l, NQ8, 16.f);
  presplit<false><<<dim3(2048), blk256, 0, stream>>>(Wk, wk_h, nullptr, NW8, 16.f);
  // 4. kk[s'][e] = sum_d key_[s'][d]*Wk[e][d] + bk[e] (col bias), hi-only out
  gemm13<2, 1, 3><<<gg, blk512, 0, stream>>>(k_h, k_l, MAT, wk_h, 0,
                                             bk, 1.f / 256.f, kk_h, nullptr, MAT);
  // 5. qk[e][s'] = sum_m qT[e][m]*kk[s'][m]  (f32 out)
  gemm13<2, 0, 0><<<gg, blk512, 0, stream>>>(qT_h, qT_l, MAT, kk_h, MAT,
                                             nullptr, 1.f / 256.f, qk, nullptr, MAT);
  // 6. P = row-softmax(qk), fp16
  softmax_rows<<<dim3(NB * Sd), blk256, 0, stream>>>(qk, P);
  // 7. presplit value (x1), Wv (x1)
  presplit<false><<<dim3(2048), blk256, 0, stream>>>(value, val_h, nullptr, NQ8, 1.f);
  presplit<false><<<dim3(2048), blk256, 0, stream>>>(Wv, wv_h, nullptr, NW8, 1.f);
  // 8. vT[d'][s'] = sum_d Wv[d'][d]*value[s'][d] + bv[d'] (row bias), fp16
  gemm13<1, 2, 1><<<gg, blk512, 0, stream>>>(wv_h, nullptr, 0, val_h, MAT,
                                             bv, 1.f, vT, nullptr, MAT);
  // 9. out[d'][e] = sum_s' vT[d'][s']*P[e][s']  (f32 -> d_out)
  gemm13<1, 0, 0><<<gg, blk512, 0, stream>>>(vT, nullptr, MAT, P, MAT,
                                             nullptr, 1.f, out, nullptr, MAT);
}